// Round 2
// baseline (473.982 us; speedup 1.0000x reference)
//
#include <hip/hip_runtime.h>

typedef unsigned short ushort_t;
typedef float  f4v  __attribute__((ext_vector_type(4)));
typedef __bf16 bf4v __attribute__((ext_vector_type(4)));
typedef __bf16 bf8v __attribute__((ext_vector_type(8)));
typedef ushort_t us4 __attribute__((ext_vector_type(4)));

#define NDIM 512
#define NCOL 65536
#define NSTEPS 20

__device__ __forceinline__ ushort_t f2bf(float f) {
  unsigned u = __float_as_uint(f);
  u = (u + 0x7fffu + ((u >> 16) & 1u)) >> 16;
  return (ushort_t)u;
}
__device__ __forceinline__ float bf2f(ushort_t h) {
  return __uint_as_float(((unsigned)h) << 16);
}

// ---------------- W^T (+ r,c zero-init folded into block (0,0)) ----------------
__global__ void transpose_k(const float* __restrict__ W, float* __restrict__ WT,
                            float* __restrict__ r, float* __restrict__ c) {
  __shared__ float tile[32][33];
  if (blockIdx.x == 0 && blockIdx.y == 0) {
    r[threadIdx.x] = 0.f; r[threadIdx.x + 256] = 0.f;
    c[threadIdx.x] = 0.f; c[threadIdx.x + 256] = 0.f;
  }
  int bx = blockIdx.x * 32, by = blockIdx.y * 32;
  int tx = threadIdx.x & 31, ty = threadIdx.x >> 5;  // 32x8
#pragma unroll
  for (int i = 0; i < 32; i += 8)
    tile[ty + i][tx] = W[(size_t)(by + ty + i) * NDIM + bx + tx];
  __syncthreads();
#pragma unroll
  for (int i = 0; i < 32; i += 8)
    WT[(size_t)(bx + ty + i) * NDIM + by + tx] = tile[tx][ty + i];
}

// ---------------- one half-iteration: dst_i = LSE_j(M[i][j] - sub[j]) ----------------
// grid 64 blocks x 512 threads; one wave per row.
__global__ void lse_step(const float* __restrict__ M, const float* __restrict__ sub,
                         float* __restrict__ dst) {
  int lane = threadIdx.x & 63;
  int wave = threadIdx.x >> 6;
  int row = blockIdx.x * 8 + wave;
  const f4v* mr = (const f4v*)(M + (size_t)row * NDIM);
  const f4v* sp = (const f4v*)sub;
  f4v a = mr[lane];
  f4v b = mr[lane + 64];
  f4v sa = sp[lane];
  f4v sb = sp[lane + 64];
  float v[8];
  v[0] = a[0] - sa[0]; v[1] = a[1] - sa[1]; v[2] = a[2] - sa[2]; v[3] = a[3] - sa[3];
  v[4] = b[0] - sb[0]; v[5] = b[1] - sb[1]; v[6] = b[2] - sb[2]; v[7] = b[3] - sb[3];
  float m = v[0];
#pragma unroll
  for (int i = 1; i < 8; ++i) m = fmaxf(m, v[i]);
#pragma unroll
  for (int off = 32; off > 0; off >>= 1) m = fmaxf(m, __shfl_xor(m, off));
  float s = 0.f;
#pragma unroll
  for (int i = 0; i < 8; ++i) s += expf(v[i] - m);
#pragma unroll
  for (int off = 32; off > 0; off >>= 1) s += __shfl_xor(s, off);
  if (lane == 0) dst[row] = m + logf(s);
}

// ---------------- dsm = exp(W - r - c), split to bf16 hi/lo ----------------
__global__ void dsm_split(const float* __restrict__ W, const float* __restrict__ r,
                          const float* __restrict__ c, ushort_t* __restrict__ Ahi,
                          ushort_t* __restrict__ Alo) {
  int idx = blockIdx.x * 256 + threadIdx.x;  // 65536 threads, 4 elems each
  int m = idx >> 7;
  int kq = idx & 127;
  f4v w = ((const f4v*)(W + (size_t)m * NDIM))[kq];
  f4v cc = ((const f4v*)c)[kq];
  float rm = r[m];
  us4 vh, vl;
#pragma unroll
  for (int i = 0; i < 4; ++i) {
    float v = expf(w[i] - rm - cc[i]);
    ushort_t h = f2bf(v);
    float res = v - bf2f(h);
    vh[i] = h;
    vl[i] = f2bf(res);
  }
  size_t base = (size_t)m * NDIM + kq * 4;
  *(us4*)(Ahi + base) = vh;
  *(us4*)(Alo + base) = vl;
}

// ---------------- GEMM: out[512][65536] = dsm @ x, 3-term bf16 split ----------------
// BM=128 BN=128 BK=32, 256 threads (4 waves 2x2), wave tile 64x64 (4x4 frags of 16x16x32).
// A (dsm hi/lo) loaded global->reg directly (L1/L2-resident, reused 512x). B (x)
// reg-staged to LDS with fp32->bf16 hi/lo split; layout [n][k] k-contig with XOR
// swizzle ((n>>2)&7)<<2 on k-index, applied on BOTH write and read (rule #21).
// Per-K-step arithmetic: ~240cy MFMA vs ~1600cy X-fetch from HBM -> X-HBM-bound;
// XCD-chunked bid swizzle makes the 4 m-blocks of an n-tile share one XCD L2 so
// X is fetched from HBM once (~128MB), not 4x.
__global__ __launch_bounds__(256, 2) void gemm_k(const float* __restrict__ X,
                                                 const ushort_t* __restrict__ Ahi,
                                                 const ushort_t* __restrict__ Alo,
                                                 float* __restrict__ out) {
  __shared__ ushort_t sBhi[128 * 32];
  __shared__ ushort_t sBlo[128 * 32];

  int bid = blockIdx.x;
  int swz = (bid & 7) * 256 + (bid >> 3);  // 2048 % 8 == 0 -> bijective
  int nt = swz >> 2;
  int mt = swz & 3;

  int tid = threadIdx.x;
  int lane = tid & 63;
  int w = tid >> 6;
  int wr = w >> 1, wc = w & 1;

  // B staging assignment: thread covers n4 = tid&31 (n = 4*n4), kpair tid>>5 and +8.
  int n4 = tid & 31;
  int fs_w = (n4 & 7) << 2;  // swizzle for rows n..n+3 (n>>2 == n4)

  // A direct-load base: row = mt*128 + wr*64 + (lane&15), k-chunk (lane>>4)*8
  const ushort_t* Abase_hi =
      Ahi + (size_t)(mt * 128 + wr * 64 + (lane & 15)) * NDIM + (lane >> 4) * 8;
  const ushort_t* Abase_lo =
      Alo + (size_t)(mt * 128 + wr * 64 + (lane & 15)) * NDIM + (lane >> 4) * 8;

  f4v acc[4][4];
#pragma unroll
  for (int i = 0; i < 4; ++i)
#pragma unroll
    for (int j = 0; j < 4; ++j) acc[i][j] = (f4v)0.f;

  for (int kt = 0; kt < 16; ++kt) {
    // ---- stage B tile [32 k][128 n] -> LDS [n][k] hi/lo, swizzled ----
#pragma unroll
    for (int it = 0; it < 2; ++it) {
      int kp = (tid >> 5) + it * 8;  // 0..15
      int k = kp * 2;
      const f4v* p0 = (const f4v*)(X + (size_t)(kt * 32 + k) * NCOL + nt * 128) + n4;
      const f4v* p1 = (const f4v*)(X + (size_t)(kt * 32 + k + 1) * NCOL + nt * 128) + n4;
      f4v va = *p0;
      f4v vb = *p1;
#pragma unroll
      for (int cx = 0; cx < 4; ++cx) {
        int nn = n4 * 4 + cx;
        float x0 = va[cx], x1 = vb[cx];
        ushort_t h0 = f2bf(x0), h1 = f2bf(x1);
        float r0 = x0 - bf2f(h0), r1 = x1 - bf2f(h1);
        ushort_t l0 = f2bf(r0), l1 = f2bf(r1);
        int idx2 = nn * 32 + (k ^ fs_w);  // even
        *(unsigned*)(&sBhi[idx2]) = (unsigned)h0 | ((unsigned)h1 << 16);
        *(unsigned*)(&sBlo[idx2]) = (unsigned)l0 | ((unsigned)l1 << 16);
      }
    }
    __syncthreads();

    // ---- A frags: global direct (L1 dedups the 2-wave wr-sharing) ----
    bf8v ah[4], al[4];
#pragma unroll
    for (int i = 0; i < 4; ++i) {
      ah[i] = *(const bf8v*)(Abase_hi + (size_t)i * 16 * NDIM + kt * 32);
      al[i] = *(const bf8v*)(Abase_lo + (size_t)i * 16 * NDIM + kt * 32);
    }
    // ---- B frags from LDS (two b64 chunks each, de-swizzled) ----
    bf8v bh[4], bl[4];
#pragma unroll
    for (int j = 0; j < 4; ++j) {
      int nn = wc * 64 + j * 16 + (lane & 15);
      int fs = ((nn >> 2) & 7) << 2;
      int kc = (lane >> 4) * 8;
      int ia = nn * 32 + (kc ^ fs);
      int ib = nn * 32 + ((kc + 4) ^ fs);
      bf4v h0 = *(const bf4v*)(&sBhi[ia]);
      bf4v h1 = *(const bf4v*)(&sBhi[ib]);
      bf4v q0 = *(const bf4v*)(&sBlo[ia]);
      bf4v q1 = *(const bf4v*)(&sBlo[ib]);
      bf8v bhv, blv;
#pragma unroll
      for (int e = 0; e < 4; ++e) {
        bhv[e] = h0[e];
        bhv[e + 4] = h1[e];
        blv[e] = q0[e];
        blv[e + 4] = q1[e];
      }
      bh[j] = bhv;
      bl[j] = blv;
    }

    // ---- 48 MFMA (3-term split: hi*hi + hi*lo + lo*hi; lo*lo ~ 2^-18, dropped) ----
#pragma unroll
    for (int i = 0; i < 4; ++i)
#pragma unroll
      for (int j = 0; j < 4; ++j) {
        acc[i][j] = __builtin_amdgcn_mfma_f32_16x16x32_bf16(ah[i], bh[j], acc[i][j], 0, 0, 0);
        acc[i][j] = __builtin_amdgcn_mfma_f32_16x16x32_bf16(ah[i], bl[j], acc[i][j], 0, 0, 0);
        acc[i][j] = __builtin_amdgcn_mfma_f32_16x16x32_bf16(al[i], bh[j], acc[i][j], 0, 0, 0);
      }
    __syncthreads();
  }

  // ---- epilogue: C/D layout col=lane&15, row=(lane>>4)*4+reg ----
  float* outp = out + (size_t)(mt * 128 + wr * 64 + (lane >> 4) * 4) * NCOL + nt * 128 +
                wc * 64 + (lane & 15);
#pragma unroll
  for (int i = 0; i < 4; ++i)
#pragma unroll
    for (int j = 0; j < 4; ++j)
#pragma unroll
      for (int rr = 0; rr < 4; ++rr)
        outp[(size_t)(i * 16 + rr) * NCOL + j * 16] = acc[i][j][rr];
}

// ---------------- launch ----------------
extern "C" void kernel_launch(void* const* d_in, const int* in_sizes, int n_in,
                              void* d_out, int out_size, void* d_ws, size_t ws_size,
                              hipStream_t stream) {
  const float* X = (const float*)d_in[0];   // [512][65536]
  const float* W = (const float*)d_in[1];   // [512][512]
  float* out = (float*)d_out;               // [512][65536]

  float* r = (float*)d_ws;
  float* c = r + NDIM;
  float* WT = c + NDIM;                     // 512*512 f32
  ushort_t* Ahi = (ushort_t*)(WT + NDIM * NDIM);
  ushort_t* Alo = Ahi + NDIM * NDIM;
  // ws usage: (1024 + 262144)*4 + 2*262144*2 ~= 2.1 MB

  transpose_k<<<dim3(16, 16), 256, 0, stream>>>(W, WT, r, c);
  for (int it = 0; it < NSTEPS; ++it) {
    lse_step<<<64, 512, 0, stream>>>(W, c, r);   // r_i = LSE_j(W - c)
    lse_step<<<64, 512, 0, stream>>>(WT, r, c);  // c_j = LSE_i(W - r)
  }
  dsm_split<<<256, 256, 0, stream>>>(W, r, c, Ahi, Alo);
  gemm_k<<<2048, 256, 0, stream>>>(X, Ahi, Alo, out);
}